// Round 4
// baseline (109.791 us; speedup 1.0000x reference)
//
#include <hip/hip_runtime.h>
#include <hip/hip_bf16.h>

#define HH 256
#define WW 256
#define CC 128
#define NN 4
#define NSS 5
#define INV_TEMP 10.0f
#define EPSI 1e-6f
#define ROWB (WW * CC * 2)     // 65536 B per image row (256 px * 256 B)
#define SC 144                 // staged cols per row window (c0-8 .. c0+135)
#define SBYTES (SC * 256)      // 36864 B per staged row

typedef __attribute__((ext_vector_type(4))) float f32x4;
typedef __attribute__((ext_vector_type(8))) short short8v;

__device__ __forceinline__ void gload_lds16(const void* g, void* l) {
    __builtin_amdgcn_global_load_lds(
        (const __attribute__((address_space(1))) unsigned int*)g,
        (__attribute__((address_space(3))) unsigned int*)l, 16, 0, 0);
}

// ---------------- Kernel A: L2-normalize over C, NCHW(f32) -> NHWC(bf16), ----------------
// ---------------- granule-swizzled: 16B granule g of pixel w stored at g^(w&7) ------------
__global__ __launch_bounds__(256) void norm_pack(const float* __restrict__ feat,
                                                 __hip_bfloat16* __restrict__ out) {
    __shared__ float lds[64][CC + 2];
    __shared__ float psum[4][64];
    __shared__ float inv[64];
    int bid = blockIdx.x;            // n*1024 + h*4 + wq
    int wq = bid & 3;
    int h = (bid >> 2) & 255;
    int n = bid >> 10;
    int tid = threadIdx.x;
    int p = tid & 63;
    int cg = tid >> 6;
    size_t base = ((size_t)(n * CC) * HH + h) * WW + wq * 64 + p;
    float ss = 0.f;
    #pragma unroll
    for (int i = 0; i < 32; ++i) {
        int c = cg * 32 + i;
        float v = feat[base + (size_t)c * (HH * WW)];
        lds[p][c] = v;
        ss += v * v;
    }
    psum[cg][p] = ss;
    __syncthreads();
    if (tid < 64) {
        float s = psum[0][tid] + psum[1][tid] + psum[2][tid] + psum[3][tid];
        inv[tid] = 1.0f / fmaxf(sqrtf(s), 1e-12f);
    }
    __syncthreads();
    __hip_bfloat16* dst = out + (((size_t)n * HH + h) * WW + wq * 64) * CC;
    #pragma unroll
    for (int k = 0; k < 4; ++k) {
        int j = (k * 256 + tid) * 8;
        int pp = j >> 7;
        int c0 = j & 127;
        int g = c0 >> 3;
        int gs = g ^ (pp & 7);           // (wq*64+pp)&7 == pp&7
        float iv = inv[pp];
        __hip_bfloat16 tmp[8];
        #pragma unroll
        for (int i = 0; i < 8; ++i)
            tmp[i] = __float2bfloat16(lds[pp][c0 + i] * iv);
        *(uint4*)(dst + pp * 128 + gs * 8) = *(uint4*)tmp;
    }
}

// ---------------- Kernel B: LDS-staged banded-Gram MFMA loss ----------------
// Block = 8 waves, owns a 2-row x 128-col tile. Wave owns 16 cols x both rows:
// the two B-tiles (at -8,+8) are shared by both row M-tiles (2:1 MFMA:ds_read).
// 2 blocks/CU resident (72KB dbuf each) so barrier stalls overlap across blocks.
// C layout (m89): col=lane&15 (neighbor), row=(lane>>4)*4+reg (own).
__global__ __launch_bounds__(512, 4) void loss_mfma(const char* __restrict__ fn,
                                                    float* __restrict__ out) {
    extern __shared__ char smem[];
    int bid = blockIdx.x;
    int swz = (bid & 7) * 128 + (bid >> 3);   // 1024 blocks, bijective
    int n  = swz >> 8;
    int h0 = ((swz >> 1) & 127) * 2;
    int c0 = (swz & 1) * 128;
    int tid = threadIdx.x;
    int wave = tid >> 6, lane = tid & 63;
    int nloc = lane & 15, kq = lane >> 4;
    int wbase = c0 + wave * 16;
    int sc0 = c0 - 8;

    const char* img = fn + (size_t)n * ((size_t)HH * ROWB);

    // A fragments: rows h0,h0+1 at col wbase+nloc (swizzled global layout)
    short8v a[2][4];
    {
        int px = wbase + nloc;
        #pragma unroll
        for (int t = 0; t < 2; ++t) {
            const char* pb = img + (size_t)(h0 + t) * ROWB + px * 256;
            #pragma unroll
            for (int kb = 0; kb < 4; ++kb)
                a[t][kb] = *(const short8v*)(pb + (((kb * 4 + kq) ^ (px & 7)) << 4));
        }
    }

    // B-fragment LDS offsets (2 tiles at wbase-8, wbase+8), buffer-local cols
    int boff[2][4];
    #pragma unroll
    for (int j = 0; j < 2; ++j) {
        int colr = wbase - 8 + 16 * j + nloc;     // in [c0-8, c0+135]
        int lcol = colr - sc0;                    // 0..143, always staged
        int cc = min(max(colr, 0), WW - 1);       // pixel actually stored there
        #pragma unroll
        for (int kb = 0; kb < 4; ++kb)
            boff[j][kb] = lcol * 256 + (((kb * 4 + kq) ^ (cc & 7)) << 4);
    }

    // validity bits per (bt, reg): band |dx|<=5 and neighbor col in image
    unsigned mb = 0;
    #pragma unroll
    for (int rr = 0; rr < 4; ++rr) {
        int rm = kq * 4 + rr;
        #pragma unroll
        for (int bt = 0; bt < 2; ++bt) {
            int off = bt ? 8 : -8;
            int dx = off + nloc - rm;
            int ncol = wbase + off + nloc;
            if (dx >= -NSS && dx <= NSS && ncol >= 0 && ncol < WW)
                mb |= 1u << (bt * 4 + rr);
        }
    }

    f32x4 eacc[2][2];
    float dsum[2][4];
    #pragma unroll
    for (int t = 0; t < 2; ++t)
        #pragma unroll
        for (int bt = 0; bt < 2; ++bt) {
            eacc[t][bt][0] = EPSI; eacc[t][bt][1] = EPSI;
            eacc[t][bt][2] = EPSI; eacc[t][bt][3] = EPSI;
        }
    #pragma unroll
    for (int t = 0; t < 2; ++t)
        #pragma unroll
        for (int rr = 0; rr < 4; ++rr) dsum[t][rr] = 0.f;

#define PROC1(cc_, T, BT, R) { \
    float d_ = (cc_)[R]; \
    float m_ = (mb & (1u << ((BT) * 4 + (R)))) ? 1.0f : 0.0f; \
    eacc[T][BT][R] += m_ * __expf(d_ * INV_TEMP); \
    dsum[T][R] += m_ * d_; \
}
#define PROC(cc_, T, BT) PROC1(cc_, T, BT, 0) PROC1(cc_, T, BT, 1) PROC1(cc_, T, BT, 2) PROC1(cc_, T, BT, 3)

    // stage one row-window (144 cols, source col clamped into image)
#define STAGE(rr_, buf_) { \
    const char* srcrow_ = img + (size_t)(rr_) * ROWB; \
    _Pragma("unroll") \
    for (int i_ = 0; i_ < 4; ++i_) { \
        int c_ = i_ * 512 + tid; \
        int cc_ = min(max(sc0 + (c_ >> 4), 0), WW - 1); \
        gload_lds16(srcrow_ + cc_ * 256 + ((c_ & 15) << 4), (buf_) + (c_ << 4)); \
    } \
    if (tid < 256) { \
        int c_ = 2048 + tid; \
        int cc_ = min(max(sc0 + (c_ >> 4), 0), WW - 1); \
        gload_lds16(srcrow_ + cc_ * 256 + ((c_ & 15) << 4), (buf_) + (c_ << 4)); \
    } \
}

    int rs = max(h0 - NSS, 0);
    int re = min(h0 + 1 + NSS, HH - 1);

    STAGE(rs, smem);

    for (int r = rs; r <= re; ++r) {
        char* cbuf = smem + ((r - rs) & 1) * SBYTES;
        if (r < re) {
            char* nbuf = smem + ((((r - rs) & 1) ^ 1) * SBYTES);
            STAGE(r + 1, nbuf);
            // wait: previous stage complete, next stage stays in flight
            if (wave < 4) asm volatile("s_waitcnt vmcnt(5)" ::: "memory");
            else          asm volatile("s_waitcnt vmcnt(4)" ::: "memory");
        } else {
            asm volatile("s_waitcnt vmcnt(0)" ::: "memory");
        }
        __builtin_amdgcn_s_barrier();
        asm volatile("" ::: "memory");

        short8v b0[4], b1[4];
        #pragma unroll
        for (int kb = 0; kb < 4; ++kb) b0[kb] = *(const short8v*)(cbuf + boff[0][kb]);
        #pragma unroll
        for (int kb = 0; kb < 4; ++kb) b1[kb] = *(const short8v*)(cbuf + boff[1][kb]);

        if (r <= h0 + NSS) {                    // row h0 in window (r>=h0-5 implied)
            f32x4 c00 = {0.f, 0.f, 0.f, 0.f};
            #pragma unroll
            for (int kb = 0; kb < 4; ++kb)
                c00 = __builtin_amdgcn_mfma_f32_16x16x32_bf16(a[0][kb], b0[kb], c00, 0, 0, 0);
            f32x4 c01 = {0.f, 0.f, 0.f, 0.f};
            #pragma unroll
            for (int kb = 0; kb < 4; ++kb)
                c01 = __builtin_amdgcn_mfma_f32_16x16x32_bf16(a[0][kb], b1[kb], c01, 0, 0, 0);
            PROC(c00, 0, 0)
            PROC(c01, 0, 1)
        }
        if (r >= h0 + 1 - NSS) {                // row h0+1 in window (r<=h0+6 implied)
            f32x4 c10 = {0.f, 0.f, 0.f, 0.f};
            #pragma unroll
            for (int kb = 0; kb < 4; ++kb)
                c10 = __builtin_amdgcn_mfma_f32_16x16x32_bf16(a[1][kb], b0[kb], c10, 0, 0, 0);
            f32x4 c11 = {0.f, 0.f, 0.f, 0.f};
            #pragma unroll
            for (int kb = 0; kb < 4; ++kb)
                c11 = __builtin_amdgcn_mfma_f32_16x16x32_bf16(a[1][kb], b1[kb], c11, 0, 0, 0);
            PROC(c10, 1, 0)
            PROC(c11, 1, 1)
        }
        __builtin_amdgcn_s_barrier();
    }

    // Epilogue: fold weights, reduce (buffers dead after final barrier -> reuse smem)
    float acc = 0.f;
    #pragma unroll
    for (int t = 0; t < 2; ++t) {
        int row = h0 + t;
        float nvd = (float)(min(NSS, row) + min(NSS, HH - 1 - row) + 1);
        #pragma unroll
        for (int rr = 0; rr < 4; ++rr) {
            int wm = wbase + kq * 4 + rr;
            int nwd = min(NSS, wm) + min(NSS, WW - 1 - wm) + 1;
            float iw = 1.0f / (nvd * (float)nwd);
            float lg = 0.f;
            #pragma unroll
            for (int bt = 0; bt < 2; ++bt) {
                float m_ = (mb & (1u << (bt * 4 + rr))) ? 1.0f : 0.0f;
                lg += m_ * __logf(eacc[t][bt][rr]);
            }
            acc += iw * (nvd * lg - INV_TEMP * dsum[t][rr]);
        }
    }
    float tot = acc * (1.0f / (4.0f * 65536.0f));
    #pragma unroll
    for (int off = 32; off >= 1; off >>= 1)
        tot += __shfl_down(tot, off);
    float* wsum = (float*)smem;
    if (lane == 0) wsum[wave] = tot;
    __syncthreads();
    if (tid == 0) {
        float s = wsum[0] + wsum[1] + wsum[2] + wsum[3]
                + wsum[4] + wsum[5] + wsum[6] + wsum[7];
        atomicAdd(out, s);
    }
}

extern "C" void kernel_launch(void* const* d_in, const int* in_sizes, int n_in,
                              void* d_out, int out_size, void* d_ws, size_t ws_size,
                              hipStream_t stream) {
    const float* feat = (const float*)d_in[0];
    float* out = (float*)d_out;
    __hip_bfloat16* fnorm = (__hip_bfloat16*)d_ws;  // 64MB

    hipFuncSetAttribute(reinterpret_cast<const void*>(&loss_mfma),
                        hipFuncAttributeMaxDynamicSharedMemorySize, 2 * SBYTES);

    hipMemsetAsync(d_out, 0, sizeof(float), stream);
    norm_pack<<<NN * HH * (WW / 64), 256, 0, stream>>>(feat, fnorm);
    loss_mfma<<<NN * HH, 512, 2 * SBYTES, stream>>>((const char*)fnorm, out);
}